// Round 1
// baseline (23.832 us; speedup 1.0000x reference)
//
#include <hip/hip_runtime.h>

// LogitDistance: out = sum_b sum_{i<j} |p[b,i]-p[b,j]| / (ntriu * B * N)
// Computed as full ordered-pair sum / 2. VALU-bound: ~537M lane-ops.

#define N 4096
#define THREADS 256
#define R 8        // i-values per thread
#define JSEG 256   // j-values staged in LDS per block

__global__ __launch_bounds__(THREADS) void pairdist_partial(
    const float* __restrict__ pred, float* __restrict__ partials, int B)
{
    const int IPB = THREADS * R;     // 2048 i per block
    const int nbi = N / IPB;         // 2
    const int nbj = N / JSEG;        // 16

    int blk = blockIdx.x;
    int jb  = blk % nbj;
    int ib  = (blk / nbj) % nbi;
    int b   = blk / (nbj * nbi);

    const float* __restrict__ row = pred + (size_t)b * N;

    __shared__ float sj[JSEG];
    sj[threadIdx.x] = row[jb * JSEG + threadIdx.x];

    // load this thread's 8 i-values (coalesced: stride-256 groups)
    float pi[R];
#pragma unroll
    for (int k = 0; k < R; ++k)
        pi[k] = row[ib * IPB + k * THREADS + threadIdx.x];

    __syncthreads();

    float acc[R];
#pragma unroll
    for (int k = 0; k < R; ++k) acc[k] = 0.0f;

    // inner loop: broadcast float4 LDS reads; 64 VALU ops per ds_read_b128
#pragma unroll 4
    for (int j = 0; j < JSEG; j += 4) {
        float4 jv = *reinterpret_cast<const float4*>(&sj[j]);
#pragma unroll
        for (int k = 0; k < R; ++k) {
            acc[k] += fabsf(pi[k] - jv.x);
            acc[k] += fabsf(pi[k] - jv.y);
            acc[k] += fabsf(pi[k] - jv.z);
            acc[k] += fabsf(pi[k] - jv.w);
        }
    }

    float t = 0.0f;
#pragma unroll
    for (int k = 0; k < R; ++k) t += acc[k];

    // wave-64 reduce
#pragma unroll
    for (int off = 32; off > 0; off >>= 1)
        t += __shfl_down(t, off, 64);

    __shared__ float swave[THREADS / 64];
    int lane = threadIdx.x & 63;
    int wid  = threadIdx.x >> 6;
    if (lane == 0) swave[wid] = t;
    __syncthreads();
    if (threadIdx.x == 0) {
        float s = 0.0f;
#pragma unroll
        for (int w = 0; w < THREADS / 64; ++w) s += swave[w];
        partials[blk] = s;
    }
}

__global__ __launch_bounds__(256) void pairdist_finalize(
    const float* __restrict__ partials, int nb, float* __restrict__ out,
    double scale)
{
    __shared__ double sd[256];
    double s = 0.0;
    for (int i = threadIdx.x; i < nb; i += 256) s += (double)partials[i];
    sd[threadIdx.x] = s;
    __syncthreads();
    for (int off = 128; off > 0; off >>= 1) {
        if (threadIdx.x < off) sd[threadIdx.x] += sd[threadIdx.x + off];
        __syncthreads();
    }
    if (threadIdx.x == 0) out[0] = (float)(sd[0] * scale);
}

extern "C" void kernel_launch(void* const* d_in, const int* in_sizes, int n_in,
                              void* d_out, int out_size, void* d_ws, size_t ws_size,
                              hipStream_t stream) {
    const float* pred = (const float*)d_in[0];
    int total = in_sizes[0];
    int B = total / N;                       // 16

    const int nbi = N / (THREADS * R);       // 2
    const int nbj = N / JSEG;                // 16
    int nb = B * nbi * nbj;                  // 512 blocks

    float* partials = (float*)d_ws;          // needs nb*4 = 2 KB of scratch

    pairdist_partial<<<nb, THREADS, 0, stream>>>(pred, partials, B);

    double ntriu = (double)N * (double)(N - 1) * 0.5;
    double scale = 1.0 / (2.0 * ntriu * (double)B * (double)N);
    pairdist_finalize<<<1, 256, 0, stream>>>(partials, nb, (float*)d_out, scale);
}